// Round 15
// baseline (776.298 us; speedup 1.0000x reference)
//
#include <hip/hip_runtime.h>
#include <cstdint>
#include <cstddef>

#define BB 8
#define TT 1536
#define DD 512
#define HH 8
#define HDD 64
#define LL 4
#define MROWS (BB*TT)   // 12288
#define QTILE 128
#define KVROWS 144      // QTILE + 16 halo

typedef __bf16 bf16;
typedef __bf16 bf16x8 __attribute__((ext_vector_type(8)));
typedef float f32x4 __attribute__((ext_vector_type(4)));

typedef void as1_void __attribute__((address_space(1)));
typedef void as3_void __attribute__((address_space(3)));

__device__ __forceinline__ void gload16(const bf16* g, bf16* l) {
  __builtin_amdgcn_global_load_lds((as1_void*)g, (as3_void*)l, 16, 0, 0);
}

// sigmoid-approx GELU as a NOINLINE call: the call boundary keeps the GEMM
// epilogue's register allocation lean (r6: call-form => VGPR 80 => 6 blocks/CU
// residency on the 1536-block sbuf GEMMs; inlined form => 92 => 5 blocks, -5%).
__device__ __attribute__((noinline)) float gelu_call(float v) {
  return v / (1.0f + __expf(-1.702f * v));
}

// ---------------- weight fp32 -> bf16 ----------------
__global__ void cvt_f2b(const float* __restrict__ in, bf16* __restrict__ out, int n4) {
  int i = blockIdx.x * blockDim.x + threadIdx.x;
  if (i >= n4) return;
  float4 v = ((const float4*)in)[i];
  union { bf16 h[4]; uint2 u; } p;
  p.h[0] = (bf16)v.x; p.h[1] = (bf16)v.y; p.h[2] = (bf16)v.z; p.h[3] = (bf16)v.w;
  ((uint2*)out)[i] = p.u;
}

// ---------------- sinusoidal PE table (T x D fp32) ----------------
__global__ void pe_kernel(float* __restrict__ pe) {
  int i = blockIdx.x * blockDim.x + threadIdx.x;   // over T*(D/2)
  if (i >= TT * (DD / 2)) return;
  int t = i / (DD / 2), k = i % (DD / 2);
  float div = expf((2.0f * (float)k) * (-9.210340371976184f / (float)DD));
  float ang = (float)t * div;
  pe[(size_t)t * DD + 2 * k]     = sinf(ang);
  pe[(size_t)t * DD + 2 * k + 1] = cosf(ang);
}

// ---------------- depthwise conv k=5 pad=2 (+bias) -> bf16, float4 ----------------
// Also emits xb = bf16 copy of x (center tap) so the front GEMM's residual read
// is 12.6 MB bf16 instead of 50 MB fp32.
__global__ void conv_dw(const float* __restrict__ x, const float* __restrict__ kw,
                        const float* __restrict__ kb, bf16* __restrict__ out,
                        bf16* __restrict__ xb) {
  int idx = blockIdx.x * 256 + threadIdx.x;        // over B*T*(D/4)
  int d4 = idx & (DD / 4 - 1);
  int bt = idx >> 7;                               // D/4=128
  int t = bt % TT;
  float4 acc = ((const float4*)kb)[d4];
  float4 ctr;
  #pragma unroll
  for (int w = 0; w < 5; ++w) {
    int tt = t + w - 2;
    if (tt >= 0 && tt < TT) {
      float4 xv = ((const float4*)(x + (size_t)(bt + (w - 2)) * DD))[d4];
      float4 kv = ((const float4*)(kw + w * DD))[d4];
      if (w == 2) ctr = xv;
      acc.x += xv.x * kv.x; acc.y += xv.y * kv.y;
      acc.z += xv.z * kv.z; acc.w += xv.w * kv.w;
    }
  }
  union { bf16 h[4]; uint2 u; } p;
  p.h[0] = (bf16)acc.x; p.h[1] = (bf16)acc.y; p.h[2] = (bf16)acc.z; p.h[3] = (bf16)acc.w;
  ((uint2*)out)[idx] = p.u;
  p.h[0] = (bf16)ctr.x; p.h[1] = (bf16)ctr.y; p.h[2] = (bf16)ctr.z; p.h[3] = (bf16)ctr.w;
  ((uint2*)xb)[idx] = p.u;
}

// ---------------- LayerNorm (row=512) fp32 -> bf16, wave per row ----------------
__global__ __launch_bounds__(256) void ln_kernel(const float* __restrict__ x,
    const float* __restrict__ w, const float* __restrict__ b, bf16* __restrict__ y) {
  int l = threadIdx.x & 63;
  int row = blockIdx.x * 4 + (threadIdx.x >> 6);
  const float4* xr = (const float4*)(x + (size_t)row * DD);
  union F8 { float4 v[2]; float f[8]; };
  F8 xv, wv, bv;
  xv.v[0] = xr[l * 2]; xv.v[1] = xr[l * 2 + 1];
  float s = 0.f, q = 0.f;
  #pragma unroll
  for (int e = 0; e < 8; ++e) { s += xv.f[e]; q += xv.f[e] * xv.f[e]; }
  #pragma unroll
  for (int off = 1; off < 64; off <<= 1) {
    s += __shfl_xor(s, off);
    q += __shfl_xor(q, off);
  }
  float mean = s * (1.0f / DD);
  float var  = q * (1.0f / DD) - mean * mean;
  float rstd = rsqrtf(var + 1e-5f);
  const float4* wr = (const float4*)w;
  const float4* br = (const float4*)b;
  wv.v[0] = wr[l * 2]; wv.v[1] = wr[l * 2 + 1];
  bv.v[0] = br[l * 2]; bv.v[1] = br[l * 2 + 1];
  bf16x8 o;
  #pragma unroll
  for (int e = 0; e < 8; ++e)
    o[e] = (bf16)((xv.f[e] - mean) * rstd * wv.f[e] + bv.f[e]);
  *(bf16x8*)(y + (size_t)row * DD + l * 8) = o;
}

// ---------------- fused residual-add + LayerNorm ----------------
__global__ __launch_bounds__(256) void addln_kernel(float* __restrict__ xm,
    const bf16* __restrict__ tmp, const float* __restrict__ w,
    const float* __restrict__ b, bf16* __restrict__ act) {
  int l = threadIdx.x & 63;
  int row = blockIdx.x * 4 + (threadIdx.x >> 6);
  float4* xr = (float4*)(xm + (size_t)row * DD);
  union F8 { float4 v[2]; float f[8]; };
  F8 xv, wv, bv;
  xv.v[0] = xr[l * 2]; xv.v[1] = xr[l * 2 + 1];
  bf16x8 tv = *(const bf16x8*)(tmp + (size_t)row * DD + l * 8);
  #pragma unroll
  for (int e = 0; e < 8; ++e) xv.f[e] += (float)tv[e];
  float s = 0.f, q = 0.f;
  #pragma unroll
  for (int e = 0; e < 8; ++e) { s += xv.f[e]; q += xv.f[e] * xv.f[e]; }
  #pragma unroll
  for (int off = 1; off < 64; off <<= 1) {
    s += __shfl_xor(s, off);
    q += __shfl_xor(q, off);
  }
  float mean = s * (1.0f / DD);
  float var  = q * (1.0f / DD) - mean * mean;
  float rstd = rsqrtf(var + 1e-5f);
  xr[l * 2] = xv.v[0];
  xr[l * 2 + 1] = xv.v[1];
  const float4* wr = (const float4*)w;
  const float4* br = (const float4*)b;
  wv.v[0] = wr[l * 2]; wv.v[1] = wr[l * 2 + 1];
  bv.v[0] = br[l * 2]; bv.v[1] = br[l * 2 + 1];
  bf16x8 o;
  #pragma unroll
  for (int e = 0; e < 8; ++e)
    o[e] = (bf16)((xv.f[e] - mean) * rstd * wv.f[e] + bv.f[e]);
  *(bf16x8*)(act + (size_t)row * DD + l * 8) = o;
}

// ---------------- sliding-window attention, LDS-staged K/V ----------------
__global__ __launch_bounds__(256) void attn_kernel(const bf16* __restrict__ qkv,
    const unsigned char* __restrict__ pad, bf16* __restrict__ o) {
  __shared__ bf16 skv[2 * KVROWS * 64];            // chunks of 8 bf16 (16B)
  int tid = threadIdx.x;
  int w = tid >> 6, l = tid & 63;
  int g = l >> 3, s = l & 7;
  int blk = blockIdx.x;                            // over B*H*(T/QTILE)
  int tile = blk % (TT / QTILE);
  int bh = blk / (TT / QTILE);
  int h = bh & (HH - 1);
  int b = bh >> 3;
  int t0 = tile * QTILE;
  int base_row = t0 - 8;
  const size_t rstr = 3 * DD;
  const bf16* qkv_b = qkv + (size_t)(b * TT) * rstr + h * HDD;

  #pragma unroll
  for (int p = 0; p < 9; ++p) {
    int gi = p * 256 + tid;
    int tensor = gi >= (KVROWS * 8);
    int gg = gi - tensor * (KVROWS * 8);
    int rl = gg >> 3, c = gg & 7;
    int sr = base_row + rl;
    sr = sr < 0 ? 0 : (sr >= TT ? TT - 1 : sr);
    const bf16* src = qkv_b + (size_t)sr * rstr + (tensor + 1) * DD + c * 8;
    gload16(src, &skv[(size_t)(p * 256 + (w << 6)) * 8]);
  }
  __syncthreads();

  const float scale = 0.125f;                      // 1/sqrt(64)
  const unsigned char* padb = pad + b * TT;
  #pragma unroll
  for (int it = 0; it < 4; ++it) {
    int t = t0 + w * 32 + it * 8 + g;
    float q[8];
    {
      bf16x8 qv = *(const bf16x8*)(qkv_b + (size_t)t * rstr + s * 8);
      #pragma unroll
      for (int e = 0; e < 8; ++e) q[e] = (float)qv[e] * scale;
    }
    float sc[11];
    #pragma unroll
    for (int jj = 0; jj < 11; ++jj) {
      int j = t - 5 + jj;
      bool ok = (j >= 0) && (j < TT);
      int jc = ok ? j : t;
      int rl = jc - base_row;
      bf16x8 kv = *(const bf16x8*)&skv[rl * 64 + s * 8];
      float sv = 0.f;
      #pragma unroll
      for (int e = 0; e < 8; ++e) sv += q[e] * (float)kv[e];
      sv += __shfl_xor(sv, 1);
      sv += __shfl_xor(sv, 2);
      sv += __shfl_xor(sv, 4);
      if (padb[jc]) sv -= 1e9f;
      sc[jj] = ok ? sv : -3.0e38f;
    }
    float m = sc[0];
    #pragma unroll
    for (int jj = 1; jj < 11; ++jj) m = fmaxf(m, sc[jj]);
    float den = 0.f;
    float acc[8] = {};
    #pragma unroll
    for (int jj = 0; jj < 11; ++jj) {
      float p = __expf(sc[jj] - m);
      den += p;
      int j = t - 5 + jj;
      int jc = (j >= 0 && j < TT) ? j : t;
      int rl = jc - base_row;
      bf16x8 vv = *(const bf16x8*)&skv[KVROWS * 64 + rl * 64 + s * 8];
      #pragma unroll
      for (int e = 0; e < 8; ++e) acc[e] += p * (float)vv[e];
    }
    float rd = 1.0f / den;
    bf16x8 ov;
    #pragma unroll
    for (int e = 0; e < 8; ++e) ov[e] = (bf16)(acc[e] * rd);
    *(bf16x8*)(o + (size_t)(b * TT + t) * DD + h * HDD + s * 8) = ov;
  }
}

// ---------------- bf16 MFMA GEMM: C = A[M][K] * Bw[N][K]^T (+epilogue) ----------------
// MODE 0: Cb = acc + bias; 1: Cb = gelu(acc+bias); 2: Cf += acc+bias;
// MODE 3: Cf = residb + gelu(acc+bias) + pe   (residb = bf16 residual)
template<int MODE, int BM, int BN, int NW, bool DBUF, int MINW>
__global__ __launch_bounds__(NW * 64, MINW) void gemm_bt(
    const bf16* __restrict__ A, const bf16* __restrict__ Bw,
    const float* __restrict__ bias, const float* __restrict__ pe,
    const bf16* __restrict__ residb, float* __restrict__ Cf, bf16* __restrict__ Cb,
    int M, int N, int K)
{
  constexpr int WCW = BN / 64;           // waves along N
  constexpr int MW  = NW / WCW;          // waves along M
  constexpr int WR  = BM / MW;           // rows per wave tile
  constexpr int RI  = WR / 16;           // 16-row fragments per wave
  constexpr int TPB = NW * 64;
  constexpr int RPP = TPB / 8;           // rows staged per pass
  constexpr int NB  = DBUF ? 2 : 1;
  __shared__ bf16 sA[NB * BM * 64];
  __shared__ bf16 sB[NB * BN * 64];
  int tid = threadIdx.x;
  int w = tid >> 6, l = tid & 63;
  int wr = w / WCW, wc = w % WCW;

  // XCD-aware remap (bijective; gridDim.y % 8 == 0 in all launches)
  int lin = blockIdx.x + gridDim.x * blockIdx.y;
  int GX = gridDim.x;
  int r8 = lin & 7, q8 = lin >> 3;
  int bx = q8 % GX;
  int by = r8 + 8 * (q8 / GX);
  int m0 = by * BM, n0 = bx * BN;
  f32x4 acc[RI][4] = {};

  int srow = tid >> 3;                   // 0..RPP-1
  int scg  = (tid & 7) ^ (srow & 7);     // pre-swizzled source col-group (rule #21)
  const bf16* Abase = A + (size_t)m0 * K + scg * 8;
  const bf16* Bbase = Bw + (size_t)n0 * K + scg * 8;

  auto stage = [&](int buf, int k0) {
    bf16* dA = sA + buf * (BM * 64);
    bf16* dB = sB + buf * (BN * 64);
    #pragma unroll
    for (int it = 0; it < BM / RPP; ++it) {
      int row = it * RPP + srow;
      gload16(Abase + (size_t)row * K + k0, dA + (it * RPP + (w << 3)) * 64);
    }
    #pragma unroll
    for (int it = 0; it < BN / RPP; ++it) {
      int row = it * RPP + srow;
      gload16(Bbase + (size_t)row * K + k0, dB + (it * RPP + (w << 3)) * 64);
    }
  };

  auto compute = [&](int buf) {
    const bf16* cA = sA + buf * (BM * 64);
    const bf16* cB = sB + buf * (BN * 64);
    #pragma unroll
    for (int kk = 0; kk < 2; ++kk) {
      bf16x8 av[RI], bv[4];
      #pragma unroll
      for (int i = 0; i < RI; ++i) {
        int ar = wr * WR + i * 16 + (l & 15);
        int aq = ((kk << 2) + (l >> 4)) ^ (ar & 7);
        av[i] = *(const bf16x8*)&cA[ar * 64 + aq * 8];
      }
      #pragma unroll
      for (int j = 0; j < 4; ++j) {
        int br = wc * 64 + j * 16 + (l & 15);
        int bq = ((kk << 2) + (l >> 4)) ^ (br & 7);
        bv[j] = *(const bf16x8*)&cB[br * 64 + bq * 8];
      }
      #pragma unroll
      for (int i = 0; i < RI; ++i)
        #pragma unroll
        for (int j = 0; j < 4; ++j)
          acc[i][j] = __builtin_amdgcn_mfma_f32_16x16x32_bf16(av[i], bv[j], acc[i][j], 0, 0, 0);
    }
  };

  int NT = K >> 6;
  if (DBUF) {
    stage(0, 0);
    __syncthreads();
    for (int t = 0; t < NT; ++t) {
      if (t + 1 < NT) stage((t + 1) & 1, (t + 1) << 6);
      compute(t & 1);
      __syncthreads();
    }
  } else {
    for (int t = 0; t < NT; ++t) {
      __syncthreads();
      stage(0, t << 6);
      __syncthreads();
      compute(0);
    }
  }

  // epilogue — C/D layout: col = lane&15, row = (lane>>4)*4 + reg
  int r0 = m0 + wr * WR + ((l >> 4) << 2);
  int c0 = n0 + wc * 64 + (l & 15);
  #pragma unroll
  for (int i = 0; i < RI; ++i) {
    #pragma unroll
    for (int j = 0; j < 4; ++j) {
      int col = c0 + j * 16;
      float bsv = bias[col];
      #pragma unroll
      for (int e = 0; e < 4; ++e) {
        int row = r0 + i * 16 + e;
        size_t idx = (size_t)row * N + col;
        float v = acc[i][j][e] + bsv;
        if (MODE == 0) {
          Cb[idx] = (bf16)v;
        } else if (MODE == 1) {
          Cb[idx] = (bf16)gelu_call(v);
        } else if (MODE == 2) {
          Cf[idx] = Cf[idx] + v;
        } else {
          int tloc = row % TT;
          Cf[idx] = (float)residb[idx] + gelu_call(v) + pe[(size_t)tloc * DD + col];
        }
      }
    }
  }
}

extern "C" void kernel_launch(void* const* d_in, const int* in_sizes, int n_in,
                              void* d_out, int out_size, void* d_ws, size_t ws_size,
                              hipStream_t stream) {
  const float* x     = (const float*)d_in[0];
  const float* dw_w  = (const float*)d_in[1];
  const float* dw_b  = (const float*)d_in[2];
  const float* pw_w  = (const float*)d_in[3];
  const float* pw_b  = (const float*)d_in[4];
  const float* Wqkv  = (const float*)d_in[5];
  const float* bqkv  = (const float*)d_in[6];
  const float* Wo    = (const float*)d_in[7];
  const float* bo    = (const float*)d_in[8];
  const float* ln1_w = (const float*)d_in[9];
  const float* ln1_b = (const float*)d_in[10];
  const float* ln2_w = (const float*)d_in[11];
  const float* ln2_b = (const float*)d_in[12];
  const float* W1    = (const float*)d_in[13];
  const float* b1    = (const float*)d_in[14];
  const float* W2    = (const float*)d_in[15];
  const float* b2    = (const float*)d_in[16];
  const unsigned char* pad = (const unsigned char*)d_in[17];
  float* xm = (float*)d_out;

  char* p = (char*)d_ws;
  auto alloc = [&](size_t bytes) {
    char* r = p;
    p += (bytes + 255) & ~(size_t)255;
    return r;
  };
  bf16* wb_pw  = (bf16*)alloc((size_t)DD * DD * 2);
  bf16* wb_qkv = (bf16*)alloc((size_t)LL * 3 * DD * DD * 2);
  bf16* wb_wo  = (bf16*)alloc((size_t)LL * DD * DD * 2);
  bf16* wb_w1  = (bf16*)alloc((size_t)LL * 4 * DD * DD * 2);
  bf16* wb_w2  = (bf16*)alloc((size_t)LL * 4 * DD * DD * 2);
  bf16* act    = (bf16*)alloc((size_t)MROWS * DD * 2);
  bf16* big    = (bf16*)alloc((size_t)MROWS * 4 * DD * 2);
  bf16* xb     = (bf16*)alloc((size_t)MROWS * DD * 2);
  float* peb   = (float*)alloc((size_t)TT * DD * 4);

  auto cvt = [&](const float* src, bf16* dst, size_t n) {
    int n4 = (int)(n / 4);
    cvt_f2b<<<(n4 + 255) / 256, 256, 0, stream>>>(src, dst, n4);
  };
  cvt(pw_w, wb_pw, (size_t)DD * DD);
  cvt(Wqkv, wb_qkv, (size_t)LL * 3 * DD * DD);
  cvt(Wo,   wb_wo,  (size_t)LL * DD * DD);
  cvt(W1,   wb_w1,  (size_t)LL * 4 * DD * DD);
  cvt(W2,   wb_w2,  (size_t)LL * 4 * DD * DD);

  pe_kernel<<<(TT * (DD / 2) + 255) / 256, 256, 0, stream>>>(peb);
  conv_dw<<<(MROWS * DD / 4) / 256, 256, 0, stream>>>(x, dw_w, dw_b, act, xb);

  // x = xb + gelu(conv @ pw^T + pw_b) + pe   -> fp32 master in d_out
  gemm_bt<3, 64, 128, 4, true, 3><<<dim3(DD / 128, MROWS / 64), 256, 0, stream>>>(
      act, wb_pw, pw_b, peb, xb, xm, nullptr, MROWS, DD, DD);
  // ln1 (layer 0) from master
  ln_kernel<<<MROWS / 4, 256, 0, stream>>>(xm, ln1_w, ln1_b, act);

  for (int layer = 0; layer < LL; ++layer) {
    // act holds LN1 output (from ln_kernel or previous addln)
    gemm_bt<0, 128, 128, 4, false, 6><<<dim3(3 * DD / 128, MROWS / 128), 256, 0, stream>>>(
        act, wb_qkv + (size_t)layer * 3 * DD * DD, bqkv + layer * 3 * DD,
        nullptr, nullptr, nullptr, big, MROWS, 3 * DD, DD);
    attn_kernel<<<BB * HH * (TT / QTILE), 256, 0, stream>>>(big, pad, act);
    // Wo: raw delta -> big (tmp; big free between attn and W1); then fused add+LN2
    gemm_bt<0, 64, 128, 4, true, 3><<<dim3(DD / 128, MROWS / 64), 256, 0, stream>>>(
        act, wb_wo + (size_t)layer * DD * DD, bo + layer * DD,
        nullptr, nullptr, nullptr, big, MROWS, DD, DD);
    addln_kernel<<<MROWS / 4, 256, 0, stream>>>(xm, big, ln2_w + layer * DD,
                                                ln2_b + layer * DD, act);
    gemm_bt<1, 128, 128, 4, false, 6><<<dim3(4 * DD / 128, MROWS / 128), 256, 0, stream>>>(
        act, wb_w1 + (size_t)layer * 4 * DD * DD, b1 + layer * 4 * DD,
        nullptr, nullptr, nullptr, big, MROWS, 4 * DD, DD);
    if (layer < LL - 1) {
      // W2: raw delta -> act (free after W1); then fused add+LN1 of next layer
      gemm_bt<0, 64, 128, 4, true, 3><<<dim3(DD / 128, MROWS / 64), 256, 0, stream>>>(
          big, wb_w2 + (size_t)layer * 4 * DD * DD, b2 + layer * DD,
          nullptr, nullptr, nullptr, act, MROWS, DD, 4 * DD);
      addln_kernel<<<MROWS / 4, 256, 0, stream>>>(xm, act, ln1_w + (layer + 1) * DD,
                                                  ln1_b + (layer + 1) * DD, act);
    } else {
      // final W2: exact fp32 RMW into master (no LN follows)
      gemm_bt<2, 64, 128, 4, true, 3><<<dim3(DD / 128, MROWS / 64), 256, 0, stream>>>(
          big, wb_w2 + (size_t)layer * 4 * DD * DD, b2 + layer * DD,
          nullptr, nullptr, xm, nullptr, MROWS, DD, 4 * DD);
    }
  }
}

// Round 16
// 734.491 us; speedup vs baseline: 1.0569x; 1.0569x over previous
//
#include <hip/hip_runtime.h>
#include <cstdint>
#include <cstddef>

#define BB 8
#define TT 1536
#define DD 512
#define HH 8
#define HDD 64
#define LL 4
#define MROWS (BB*TT)   // 12288
#define QTILE 128
#define KVROWS 144      // QTILE + 16 halo

typedef __bf16 bf16;
typedef __bf16 bf16x8 __attribute__((ext_vector_type(8)));
typedef float f32x4 __attribute__((ext_vector_type(4)));

typedef void as1_void __attribute__((address_space(1)));
typedef void as3_void __attribute__((address_space(3)));

__device__ __forceinline__ void gload16(const bf16* g, bf16* l) {
  __builtin_amdgcn_global_load_lds((as1_void*)g, (as3_void*)l, 16, 0, 0);
}

// sigmoid-approx GELU, INLINED (r15 measured: noinline call form = VGPR 80 /
// 27% occupancy but +8us per GEMM from call overhead; inlined = VGPR 92 /
// 18% occupancy and fastest measured — occupancy was not the binding constraint).
__device__ __forceinline__ float gelu_f(float v) {
  return v / (1.0f + __expf(-1.702f * v));
}

// ---------------- weight fp32 -> bf16 ----------------
__global__ void cvt_f2b(const float* __restrict__ in, bf16* __restrict__ out, int n4) {
  int i = blockIdx.x * blockDim.x + threadIdx.x;
  if (i >= n4) return;
  float4 v = ((const float4*)in)[i];
  union { bf16 h[4]; uint2 u; } p;
  p.h[0] = (bf16)v.x; p.h[1] = (bf16)v.y; p.h[2] = (bf16)v.z; p.h[3] = (bf16)v.w;
  ((uint2*)out)[i] = p.u;
}

// ---------------- sinusoidal PE table (T x D fp32) ----------------
__global__ void pe_kernel(float* __restrict__ pe) {
  int i = blockIdx.x * blockDim.x + threadIdx.x;   // over T*(D/2)
  if (i >= TT * (DD / 2)) return;
  int t = i / (DD / 2), k = i % (DD / 2);
  float div = expf((2.0f * (float)k) * (-9.210340371976184f / (float)DD));
  float ang = (float)t * div;
  pe[(size_t)t * DD + 2 * k]     = sinf(ang);
  pe[(size_t)t * DD + 2 * k + 1] = cosf(ang);
}

// ---------------- depthwise conv k=5 pad=2 (+bias) -> bf16, float4 ----------------
// Also emits xb = bf16 copy of x (center tap) so the front GEMM's residual read
// is 12.6 MB bf16 instead of 50 MB fp32.
__global__ void conv_dw(const float* __restrict__ x, const float* __restrict__ kw,
                        const float* __restrict__ kb, bf16* __restrict__ out,
                        bf16* __restrict__ xb) {
  int idx = blockIdx.x * 256 + threadIdx.x;        // over B*T*(D/4)
  int d4 = idx & (DD / 4 - 1);
  int bt = idx >> 7;                               // D/4=128
  int t = bt % TT;
  float4 acc = ((const float4*)kb)[d4];
  float4 ctr;
  #pragma unroll
  for (int w = 0; w < 5; ++w) {
    int tt = t + w - 2;
    if (tt >= 0 && tt < TT) {
      float4 xv = ((const float4*)(x + (size_t)(bt + (w - 2)) * DD))[d4];
      float4 kv = ((const float4*)(kw + w * DD))[d4];
      if (w == 2) ctr = xv;
      acc.x += xv.x * kv.x; acc.y += xv.y * kv.y;
      acc.z += xv.z * kv.z; acc.w += xv.w * kv.w;
    }
  }
  union { bf16 h[4]; uint2 u; } p;
  p.h[0] = (bf16)acc.x; p.h[1] = (bf16)acc.y; p.h[2] = (bf16)acc.z; p.h[3] = (bf16)acc.w;
  ((uint2*)out)[idx] = p.u;
  p.h[0] = (bf16)ctr.x; p.h[1] = (bf16)ctr.y; p.h[2] = (bf16)ctr.z; p.h[3] = (bf16)ctr.w;
  ((uint2*)xb)[idx] = p.u;
}

// ---------------- LayerNorm (row=512) fp32 -> bf16, wave per row ----------------
__global__ __launch_bounds__(256) void ln_kernel(const float* __restrict__ x,
    const float* __restrict__ w, const float* __restrict__ b, bf16* __restrict__ y) {
  int l = threadIdx.x & 63;
  int row = blockIdx.x * 4 + (threadIdx.x >> 6);
  const float4* xr = (const float4*)(x + (size_t)row * DD);
  union F8 { float4 v[2]; float f[8]; };
  F8 xv, wv, bv;
  xv.v[0] = xr[l * 2]; xv.v[1] = xr[l * 2 + 1];
  float s = 0.f, q = 0.f;
  #pragma unroll
  for (int e = 0; e < 8; ++e) { s += xv.f[e]; q += xv.f[e] * xv.f[e]; }
  #pragma unroll
  for (int off = 1; off < 64; off <<= 1) {
    s += __shfl_xor(s, off);
    q += __shfl_xor(q, off);
  }
  float mean = s * (1.0f / DD);
  float var  = q * (1.0f / DD) - mean * mean;
  float rstd = rsqrtf(var + 1e-5f);
  const float4* wr = (const float4*)w;
  const float4* br = (const float4*)b;
  wv.v[0] = wr[l * 2]; wv.v[1] = wr[l * 2 + 1];
  bv.v[0] = br[l * 2]; bv.v[1] = br[l * 2 + 1];
  bf16x8 o;
  #pragma unroll
  for (int e = 0; e < 8; ++e)
    o[e] = (bf16)((xv.f[e] - mean) * rstd * wv.f[e] + bv.f[e]);
  *(bf16x8*)(y + (size_t)row * DD + l * 8) = o;
}

// ---------------- fused residual-add + LayerNorm ----------------
__global__ __launch_bounds__(256) void addln_kernel(float* __restrict__ xm,
    const bf16* __restrict__ tmp, const float* __restrict__ w,
    const float* __restrict__ b, bf16* __restrict__ act) {
  int l = threadIdx.x & 63;
  int row = blockIdx.x * 4 + (threadIdx.x >> 6);
  float4* xr = (float4*)(xm + (size_t)row * DD);
  union F8 { float4 v[2]; float f[8]; };
  F8 xv, wv, bv;
  xv.v[0] = xr[l * 2]; xv.v[1] = xr[l * 2 + 1];
  bf16x8 tv = *(const bf16x8*)(tmp + (size_t)row * DD + l * 8);
  #pragma unroll
  for (int e = 0; e < 8; ++e) xv.f[e] += (float)tv[e];
  float s = 0.f, q = 0.f;
  #pragma unroll
  for (int e = 0; e < 8; ++e) { s += xv.f[e]; q += xv.f[e] * xv.f[e]; }
  #pragma unroll
  for (int off = 1; off < 64; off <<= 1) {
    s += __shfl_xor(s, off);
    q += __shfl_xor(q, off);
  }
  float mean = s * (1.0f / DD);
  float var  = q * (1.0f / DD) - mean * mean;
  float rstd = rsqrtf(var + 1e-5f);
  xr[l * 2] = xv.v[0];
  xr[l * 2 + 1] = xv.v[1];
  const float4* wr = (const float4*)w;
  const float4* br = (const float4*)b;
  wv.v[0] = wr[l * 2]; wv.v[1] = wr[l * 2 + 1];
  bv.v[0] = br[l * 2]; bv.v[1] = br[l * 2 + 1];
  bf16x8 o;
  #pragma unroll
  for (int e = 0; e < 8; ++e)
    o[e] = (bf16)((xv.f[e] - mean) * rstd * wv.f[e] + bv.f[e]);
  *(bf16x8*)(act + (size_t)row * DD + l * 8) = o;
}

// ---------------- sliding-window attention, LDS-staged K/V ----------------
__global__ __launch_bounds__(256) void attn_kernel(const bf16* __restrict__ qkv,
    const unsigned char* __restrict__ pad, bf16* __restrict__ o) {
  __shared__ bf16 skv[2 * KVROWS * 64];            // chunks of 8 bf16 (16B)
  int tid = threadIdx.x;
  int w = tid >> 6, l = tid & 63;
  int g = l >> 3, s = l & 7;
  int blk = blockIdx.x;                            // over B*H*(T/QTILE)
  int tile = blk % (TT / QTILE);
  int bh = blk / (TT / QTILE);
  int h = bh & (HH - 1);
  int b = bh >> 3;
  int t0 = tile * QTILE;
  int base_row = t0 - 8;
  const size_t rstr = 3 * DD;
  const bf16* qkv_b = qkv + (size_t)(b * TT) * rstr + h * HDD;

  #pragma unroll
  for (int p = 0; p < 9; ++p) {
    int gi = p * 256 + tid;
    int tensor = gi >= (KVROWS * 8);
    int gg = gi - tensor * (KVROWS * 8);
    int rl = gg >> 3, c = gg & 7;
    int sr = base_row + rl;
    sr = sr < 0 ? 0 : (sr >= TT ? TT - 1 : sr);
    const bf16* src = qkv_b + (size_t)sr * rstr + (tensor + 1) * DD + c * 8;
    gload16(src, &skv[(size_t)(p * 256 + (w << 6)) * 8]);
  }
  __syncthreads();

  const float scale = 0.125f;                      // 1/sqrt(64)
  const unsigned char* padb = pad + b * TT;
  #pragma unroll
  for (int it = 0; it < 4; ++it) {
    int t = t0 + w * 32 + it * 8 + g;
    float q[8];
    {
      bf16x8 qv = *(const bf16x8*)(qkv_b + (size_t)t * rstr + s * 8);
      #pragma unroll
      for (int e = 0; e < 8; ++e) q[e] = (float)qv[e] * scale;
    }
    float sc[11];
    #pragma unroll
    for (int jj = 0; jj < 11; ++jj) {
      int j = t - 5 + jj;
      bool ok = (j >= 0) && (j < TT);
      int jc = ok ? j : t;
      int rl = jc - base_row;
      bf16x8 kv = *(const bf16x8*)&skv[rl * 64 + s * 8];
      float sv = 0.f;
      #pragma unroll
      for (int e = 0; e < 8; ++e) sv += q[e] * (float)kv[e];
      sv += __shfl_xor(sv, 1);
      sv += __shfl_xor(sv, 2);
      sv += __shfl_xor(sv, 4);
      if (padb[jc]) sv -= 1e9f;
      sc[jj] = ok ? sv : -3.0e38f;
    }
    float m = sc[0];
    #pragma unroll
    for (int jj = 1; jj < 11; ++jj) m = fmaxf(m, sc[jj]);
    float den = 0.f;
    float acc[8] = {};
    #pragma unroll
    for (int jj = 0; jj < 11; ++jj) {
      float p = __expf(sc[jj] - m);
      den += p;
      int j = t - 5 + jj;
      int jc = (j >= 0 && j < TT) ? j : t;
      int rl = jc - base_row;
      bf16x8 vv = *(const bf16x8*)&skv[KVROWS * 64 + rl * 64 + s * 8];
      #pragma unroll
      for (int e = 0; e < 8; ++e) acc[e] += p * (float)vv[e];
    }
    float rd = 1.0f / den;
    bf16x8 ov;
    #pragma unroll
    for (int e = 0; e < 8; ++e) ov[e] = (bf16)(acc[e] * rd);
    *(bf16x8*)(o + (size_t)(b * TT + t) * DD + h * HDD + s * 8) = ov;
  }
}

// ---------------- bf16 MFMA GEMM: C = A[M][K] * Bw[N][K]^T (+epilogue) ----------------
// MODE 0: Cb = acc + bias; 1: Cb = gelu(acc+bias); 2: Cf += acc+bias;
// MODE 3: Cf = residb + gelu(acc+bias) + pe   (residb = bf16 residual)
template<int MODE, int BM, int BN, int NW, bool DBUF, int MINW>
__global__ __launch_bounds__(NW * 64, MINW) void gemm_bt(
    const bf16* __restrict__ A, const bf16* __restrict__ Bw,
    const float* __restrict__ bias, const float* __restrict__ pe,
    const bf16* __restrict__ residb, float* __restrict__ Cf, bf16* __restrict__ Cb,
    int M, int N, int K)
{
  constexpr int WCW = BN / 64;           // waves along N
  constexpr int MW  = NW / WCW;          // waves along M
  constexpr int WR  = BM / MW;           // rows per wave tile
  constexpr int RI  = WR / 16;           // 16-row fragments per wave
  constexpr int TPB = NW * 64;
  constexpr int RPP = TPB / 8;           // rows staged per pass
  constexpr int NB  = DBUF ? 2 : 1;
  __shared__ bf16 sA[NB * BM * 64];
  __shared__ bf16 sB[NB * BN * 64];
  int tid = threadIdx.x;
  int w = tid >> 6, l = tid & 63;
  int wr = w / WCW, wc = w % WCW;

  // XCD-aware remap (bijective; gridDim.y % 8 == 0 in all launches)
  int lin = blockIdx.x + gridDim.x * blockIdx.y;
  int GX = gridDim.x;
  int r8 = lin & 7, q8 = lin >> 3;
  int bx = q8 % GX;
  int by = r8 + 8 * (q8 / GX);
  int m0 = by * BM, n0 = bx * BN;
  f32x4 acc[RI][4] = {};

  int srow = tid >> 3;                   // 0..RPP-1
  int scg  = (tid & 7) ^ (srow & 7);     // pre-swizzled source col-group (rule #21)
  const bf16* Abase = A + (size_t)m0 * K + scg * 8;
  const bf16* Bbase = Bw + (size_t)n0 * K + scg * 8;

  auto stage = [&](int buf, int k0) {
    bf16* dA = sA + buf * (BM * 64);
    bf16* dB = sB + buf * (BN * 64);
    #pragma unroll
    for (int it = 0; it < BM / RPP; ++it) {
      int row = it * RPP + srow;
      gload16(Abase + (size_t)row * K + k0, dA + (it * RPP + (w << 3)) * 64);
    }
    #pragma unroll
    for (int it = 0; it < BN / RPP; ++it) {
      int row = it * RPP + srow;
      gload16(Bbase + (size_t)row * K + k0, dB + (it * RPP + (w << 3)) * 64);
    }
  };

  auto compute = [&](int buf) {
    const bf16* cA = sA + buf * (BM * 64);
    const bf16* cB = sB + buf * (BN * 64);
    #pragma unroll
    for (int kk = 0; kk < 2; ++kk) {
      bf16x8 av[RI], bv[4];
      #pragma unroll
      for (int i = 0; i < RI; ++i) {
        int ar = wr * WR + i * 16 + (l & 15);
        int aq = ((kk << 2) + (l >> 4)) ^ (ar & 7);
        av[i] = *(const bf16x8*)&cA[ar * 64 + aq * 8];
      }
      #pragma unroll
      for (int j = 0; j < 4; ++j) {
        int br = wc * 64 + j * 16 + (l & 15);
        int bq = ((kk << 2) + (l >> 4)) ^ (br & 7);
        bv[j] = *(const bf16x8*)&cB[br * 64 + bq * 8];
      }
      #pragma unroll
      for (int i = 0; i < RI; ++i)
        #pragma unroll
        for (int j = 0; j < 4; ++j)
          acc[i][j] = __builtin_amdgcn_mfma_f32_16x16x32_bf16(av[i], bv[j], acc[i][j], 0, 0, 0);
    }
  };

  int NT = K >> 6;
  if (DBUF) {
    stage(0, 0);
    __syncthreads();
    for (int t = 0; t < NT; ++t) {
      if (t + 1 < NT) stage((t + 1) & 1, (t + 1) << 6);
      compute(t & 1);
      __syncthreads();
    }
  } else {
    for (int t = 0; t < NT; ++t) {
      __syncthreads();
      stage(0, t << 6);
      __syncthreads();
      compute(0);
    }
  }

  // epilogue — C/D layout: col = lane&15, row = (lane>>4)*4 + reg
  int r0 = m0 + wr * WR + ((l >> 4) << 2);
  int c0 = n0 + wc * 64 + (l & 15);
  #pragma unroll
  for (int i = 0; i < RI; ++i) {
    #pragma unroll
    for (int j = 0; j < 4; ++j) {
      int col = c0 + j * 16;
      float bsv = bias[col];
      #pragma unroll
      for (int e = 0; e < 4; ++e) {
        int row = r0 + i * 16 + e;
        size_t idx = (size_t)row * N + col;
        float v = acc[i][j][e] + bsv;
        if (MODE == 0) {
          Cb[idx] = (bf16)v;
        } else if (MODE == 1) {
          Cb[idx] = (bf16)gelu_f(v);
        } else if (MODE == 2) {
          Cf[idx] = Cf[idx] + v;
        } else {
          int tloc = row % TT;
          Cf[idx] = (float)residb[idx] + gelu_f(v) + pe[(size_t)tloc * DD + col];
        }
      }
    }
  }
}

extern "C" void kernel_launch(void* const* d_in, const int* in_sizes, int n_in,
                              void* d_out, int out_size, void* d_ws, size_t ws_size,
                              hipStream_t stream) {
  const float* x     = (const float*)d_in[0];
  const float* dw_w  = (const float*)d_in[1];
  const float* dw_b  = (const float*)d_in[2];
  const float* pw_w  = (const float*)d_in[3];
  const float* pw_b  = (const float*)d_in[4];
  const float* Wqkv  = (const float*)d_in[5];
  const float* bqkv  = (const float*)d_in[6];
  const float* Wo    = (const float*)d_in[7];
  const float* bo    = (const float*)d_in[8];
  const float* ln1_w = (const float*)d_in[9];
  const float* ln1_b = (const float*)d_in[10];
  const float* ln2_w = (const float*)d_in[11];
  const float* ln2_b = (const float*)d_in[12];
  const float* W1    = (const float*)d_in[13];
  const float* b1    = (const float*)d_in[14];
  const float* W2    = (const float*)d_in[15];
  const float* b2    = (const float*)d_in[16];
  const unsigned char* pad = (const unsigned char*)d_in[17];
  float* xm = (float*)d_out;

  char* p = (char*)d_ws;
  auto alloc = [&](size_t bytes) {
    char* r = p;
    p += (bytes + 255) & ~(size_t)255;
    return r;
  };
  bf16* wb_pw  = (bf16*)alloc((size_t)DD * DD * 2);
  bf16* wb_qkv = (bf16*)alloc((size_t)LL * 3 * DD * DD * 2);
  bf16* wb_wo  = (bf16*)alloc((size_t)LL * DD * DD * 2);
  bf16* wb_w1  = (bf16*)alloc((size_t)LL * 4 * DD * DD * 2);
  bf16* wb_w2  = (bf16*)alloc((size_t)LL * 4 * DD * DD * 2);
  bf16* act    = (bf16*)alloc((size_t)MROWS * DD * 2);
  bf16* big    = (bf16*)alloc((size_t)MROWS * 4 * DD * 2);
  bf16* xb     = (bf16*)alloc((size_t)MROWS * DD * 2);
  float* peb   = (float*)alloc((size_t)TT * DD * 4);

  auto cvt = [&](const float* src, bf16* dst, size_t n) {
    int n4 = (int)(n / 4);
    cvt_f2b<<<(n4 + 255) / 256, 256, 0, stream>>>(src, dst, n4);
  };
  cvt(pw_w, wb_pw, (size_t)DD * DD);
  cvt(Wqkv, wb_qkv, (size_t)LL * 3 * DD * DD);
  cvt(Wo,   wb_wo,  (size_t)LL * DD * DD);
  cvt(W1,   wb_w1,  (size_t)LL * 4 * DD * DD);
  cvt(W2,   wb_w2,  (size_t)LL * 4 * DD * DD);

  pe_kernel<<<(TT * (DD / 2) + 255) / 256, 256, 0, stream>>>(peb);
  conv_dw<<<(MROWS * DD / 4) / 256, 256, 0, stream>>>(x, dw_w, dw_b, act, xb);

  // x = xb + gelu(conv @ pw^T + pw_b) + pe   -> fp32 master in d_out
  gemm_bt<3, 64, 128, 4, true, 3><<<dim3(DD / 128, MROWS / 64), 256, 0, stream>>>(
      act, wb_pw, pw_b, peb, xb, xm, nullptr, MROWS, DD, DD);
  // ln1 (layer 0) from master
  ln_kernel<<<MROWS / 4, 256, 0, stream>>>(xm, ln1_w, ln1_b, act);

  for (int layer = 0; layer < LL; ++layer) {
    // act holds LN1 output (from ln_kernel or previous addln)
    gemm_bt<0, 128, 128, 4, false, 6><<<dim3(3 * DD / 128, MROWS / 128), 256, 0, stream>>>(
        act, wb_qkv + (size_t)layer * 3 * DD * DD, bqkv + layer * 3 * DD,
        nullptr, nullptr, nullptr, big, MROWS, 3 * DD, DD);
    attn_kernel<<<BB * HH * (TT / QTILE), 256, 0, stream>>>(big, pad, act);
    // Wo: raw delta -> big (tmp; big free between attn and W1); then fused add+LN2
    gemm_bt<0, 64, 128, 4, true, 3><<<dim3(DD / 128, MROWS / 64), 256, 0, stream>>>(
        act, wb_wo + (size_t)layer * DD * DD, bo + layer * DD,
        nullptr, nullptr, nullptr, big, MROWS, DD, DD);
    addln_kernel<<<MROWS / 4, 256, 0, stream>>>(xm, big, ln2_w + layer * DD,
                                                ln2_b + layer * DD, act);
    gemm_bt<1, 128, 128, 4, false, 6><<<dim3(4 * DD / 128, MROWS / 128), 256, 0, stream>>>(
        act, wb_w1 + (size_t)layer * 4 * DD * DD, b1 + layer * 4 * DD,
        nullptr, nullptr, nullptr, big, MROWS, 4 * DD, DD);
    if (layer < LL - 1) {
      // W2: raw delta -> act (free after W1); then fused add+LN1 of next layer
      gemm_bt<0, 64, 128, 4, true, 3><<<dim3(DD / 128, MROWS / 64), 256, 0, stream>>>(
          big, wb_w2 + (size_t)layer * 4 * DD * DD, b2 + layer * DD,
          nullptr, nullptr, nullptr, act, MROWS, DD, 4 * DD);
      addln_kernel<<<MROWS / 4, 256, 0, stream>>>(xm, act, ln1_w + (layer + 1) * DD,
                                                  ln1_b + (layer + 1) * DD, act);
    } else {
      // final W2: exact fp32 RMW into master (no LN follows)
      gemm_bt<2, 64, 128, 4, true, 3><<<dim3(DD / 128, MROWS / 64), 256, 0, stream>>>(
          big, wb_w2 + (size_t)layer * 4 * DD * DD, b2 + layer * DD,
          nullptr, nullptr, xm, nullptr, MROWS, DD, 4 * DD);
    }
  }
}